// Round 10
// baseline (242.869 us; speedup 1.0000x reference)
//
#include <hip/hip_runtime.h>
#include <hip/hip_bf16.h>

// LinearAttention collapsed:
//   dots[m,h] = sum_{d in head h} (X@Wk^T)*(X@Wv^T)   [dual GEMM, A in registers f32->bf16]
//   qsum = X @ Wqs^T ; dotb = X @ CB^T                 [side GEMM: 64 trailing blocks]
//   cum = cumsum_s((dots + dotb + dbc)*mask^2); coef = cum*(qsum+bqs)
//   out = coef @ WosT + bo ; state[b,h,:,:] = cum[b, S-1, h]

typedef __attribute__((ext_vector_type(4))) float f32x4;
typedef __attribute__((ext_vector_type(8))) short bf16x8;
typedef __attribute__((ext_vector_type(8))) unsigned short u16x8;
typedef unsigned int u32;

#define GLDS16(g, l)                                                            \
  __builtin_amdgcn_global_load_lds((const __attribute__((address_space(1))) u32*)(g), \
                                   (__attribute__((address_space(3))) u32*)(l), 16, 0, 0)
#define MFMA16(a, b, c) __builtin_amdgcn_mfma_f32_16x16x32_bf16(a, b, c, 0, 0, 0)
#define LGK0 do { asm volatile("s_waitcnt lgkmcnt(0)" ::: "memory"); \
                  __builtin_amdgcn_sched_barrier(0); } while (0)

__device__ __forceinline__ unsigned short f2bf(float f) {
  union { float f; u32 u; } x; x.f = f;
  u32 r = (x.u + 0x7fffu + ((x.u >> 16) & 1u)) >> 16;
  return (unsigned short)r;
}

__device__ __forceinline__ bf16x8 pack8(const f32x4& lo, const f32x4& hi) {
  union { bf16x8 v; u32 w[4]; } r;
  union { __hip_bfloat162 h; u32 u; } c;
  c.h = __float22bfloat162_rn(make_float2(lo.x, lo.y)); r.w[0] = c.u;
  c.h = __float22bfloat162_rn(make_float2(lo.z, lo.w)); r.w[1] = c.u;
  c.h = __float22bfloat162_rn(make_float2(hi.x, hi.y)); r.w[2] = c.u;
  c.h = __float22bfloat162_rn(make_float2(hi.z, hi.w)); r.w[3] = c.u;
  return r.v;
}

// ---------------- prep: Wk/Wv->bf16 + weight sums (no X convert) ----------------
__global__ void k_prep(const float* __restrict__ Wq, const float* __restrict__ bq,
                       const float* __restrict__ Wk, const float* __restrict__ bk,
                       const float* __restrict__ Wv, const float* __restrict__ bv,
                       const float* __restrict__ Wo,
                       unsigned short* __restrict__ Wkb, unsigned short* __restrict__ Wvb,
                       unsigned short* __restrict__ SWb, float* __restrict__ WosT,
                       float* __restrict__ scal) {
  int blk = blockIdx.x, t = threadIdx.x;
  if (blk < 2048) {
    const float* src = (blk < 1024) ? Wk : Wv;
    unsigned short* dst = (blk < 1024) ? Wkb : Wvb;
    size_t i = ((size_t)(blk & 1023) * 256 + t) * 4;
    f32x4 v = *(const f32x4*)(src + i);
    dst[i + 0] = f2bf(v.x); dst[i + 1] = f2bf(v.y);
    dst[i + 2] = f2bf(v.z); dst[i + 3] = f2bf(v.w);
  } else {
    int b2 = blk - 2048;
    if (b2 < 128) {
      int o = b2 * 256 + t;
      int r = o >> 10, c = o & 1023;
      float s = 0.f;
      if (r < 16) {
        for (int d = 0; d < 64; ++d) s += Wq[(size_t)(r * 64 + d) * 1024 + c];
      } else {
        int h = r - 16;
        for (int d = 0; d < 64; ++d) {
          int j = h * 64 + d;
          s += bv[j] * Wk[(size_t)j * 1024 + c] + bk[j] * Wv[(size_t)j * 1024 + c];
        }
      }
      SWb[o] = f2bf(s);
    } else if (b2 < 192) {
      int o = (b2 - 128) * 256 + t;
      int h = o >> 10, j = o & 1023;
      float s = 0.f;
      for (int d = 0; d < 64; ++d) s += Wo[(size_t)j * 1024 + h * 64 + d];
      WosT[o] = s;
    } else {
      if (t < 16) {
        float s = 0.f;
        for (int d = 0; d < 64; ++d) s += bq[t * 64 + d];
        scal[t] = s;
      } else if (t < 32) {
        int h = t - 16;
        float s = 0.f;
        for (int d = 0; d < 64; ++d) s += bk[h * 64 + d] * bv[h * 64 + d];
        scal[t] = s;
      }
    }
  }
}

// ---------------- dual GEMM + trailing side blocks ----------------
// Blocks 0..511 (dual): BM=256, BN=128, BK=32, 8 waves (4M x 2N). A in REGISTERS
// (8x global_load_dwordx4 f32 issued one tile ahead; pack8->bf16 overlaps bk ds_reads).
// B (Wk/Wv) via global_load_lds depth-3, 4 buffers x 8192 elems = 65536 B, R2 swizzle.
// One counted vmcnt + one barrier per tile. Queue: [B(t+2)2][A(t+1)8][B(t+3)2] -> vmcnt(2).
// Blocks 512..575 (side): qsum/dotb GEMM, SW resident in padded LDS, no steady barriers.
#define NT 32
#define DBUFS 8192
__global__ __launch_bounds__(512, 2) void k_dualgemm(
    const float* __restrict__ X,
    const unsigned short* __restrict__ Wkb,
    const unsigned short* __restrict__ Wvb,
    const unsigned short* __restrict__ SWb,
    float* __restrict__ dotsT, float* __restrict__ qsumT, float* __restrict__ dotbT) {
  extern __shared__ __align__(16) unsigned short lds[];
  int orig = blockIdx.x;
  int tid = threadIdx.x, wid = tid >> 6, lane = tid & 63;
  int fr = lane & 15, fg = lane >> 4;

  if (orig >= 512) {  // ================= side path =================
    int row0 = (orig - 512) << 8;
    // SW -> padded LDS [32][1032] (once)
#pragma unroll
    for (int i = 0; i < 8; ++i) {
      int u = i * 512 + tid;
      int r = u >> 7, c = (u & 127) << 3;
      *(bf16x8*)(lds + r * 1032 + c) = *(const bf16x8*)(SWb + (size_t)r * 1024 + c);
    }
    const float* pA[2];
#pragma unroll
    for (int mi = 0; mi < 2; ++mi)
      pA[mi] = X + (size_t)(row0 + wid * 32 + mi * 16 + fr) * 1024 + fg * 8;
    f32x4 sAL[2], sAH[2], sBL[2], sBH[2];
#pragma unroll
    for (int mi = 0; mi < 2; ++mi) {
      sAL[mi] = *(const f32x4*)(pA[mi]);      sAH[mi] = *(const f32x4*)(pA[mi] + 4);
      sBL[mi] = *(const f32x4*)(pA[mi] + 32); sBH[mi] = *(const f32x4*)(pA[mi] + 36);
    }
    __syncthreads();   // SW writes visible; also drains prefetch (prologue only)
    f32x4 acc[2][2] = {{0}};
    for (int tt = 0; tt < NT; tt += 2) {
      // even tile (consume sA, refill sA for tt+2)
      {
        asm volatile("s_waitcnt vmcnt(4)" ::: "memory");
        bf16x8 a0 = pack8(sAL[0], sAH[0]);
        bf16x8 a1 = pack8(sAL[1], sAH[1]);
        int ko2 = (tt + 2 < NT) ? (tt + 2) << 5 : 0;
#pragma unroll
        for (int mi = 0; mi < 2; ++mi) {
          sAL[mi] = *(const f32x4*)(pA[mi] + ko2);
          sAH[mi] = *(const f32x4*)(pA[mi] + ko2 + 4);
        }
        int k0 = tt << 5;
        bf16x8 s0 = *(const bf16x8*)(lds + fr * 1032 + k0 + fg * 8);
        bf16x8 s1 = *(const bf16x8*)(lds + (16 + fr) * 1032 + k0 + fg * 8);
        acc[0][0] = MFMA16(a0, s0, acc[0][0]);
        acc[0][1] = MFMA16(a0, s1, acc[0][1]);
        acc[1][0] = MFMA16(a1, s0, acc[1][0]);
        acc[1][1] = MFMA16(a1, s1, acc[1][1]);
      }
      // odd tile (consume sB, refill sB for tt+3)
      {
        asm volatile("s_waitcnt vmcnt(4)" ::: "memory");
        bf16x8 a0 = pack8(sBL[0], sBH[0]);
        bf16x8 a1 = pack8(sBL[1], sBH[1]);
        int ko3 = (tt + 3 < NT) ? (tt + 3) << 5 : 0;
#pragma unroll
        for (int mi = 0; mi < 2; ++mi) {
          sBL[mi] = *(const f32x4*)(pA[mi] + ko3);
          sBH[mi] = *(const f32x4*)(pA[mi] + ko3 + 4);
        }
        int k0 = (tt + 1) << 5;
        bf16x8 s0 = *(const bf16x8*)(lds + fr * 1032 + k0 + fg * 8);
        bf16x8 s1 = *(const bf16x8*)(lds + (16 + fr) * 1032 + k0 + fg * 8);
        acc[0][0] = MFMA16(a0, s0, acc[0][0]);
        acc[0][1] = MFMA16(a0, s1, acc[0][1]);
        acc[1][0] = MFMA16(a1, s0, acc[1][0]);
        acc[1][1] = MFMA16(a1, s1, acc[1][1]);
      }
    }
    size_t mbase = row0 + wid * 32;
#pragma unroll
    for (int mi = 0; mi < 2; ++mi)
#pragma unroll
      for (int ni = 0; ni < 2; ++ni) {
        float* dst = (ni == 0) ? qsumT : dotbT;
#pragma unroll
        for (int q = 0; q < 4; ++q)
          dst[(size_t)fr * 16384 + mbase + mi * 16 + fg * 4 + q] = acc[mi][ni][q];
      }
    return;
  }

  // ================= dual path =================
  int wg = (orig & 7) * 64 + (orig >> 3);    // XCD-chunked swizzle (512 % 8 == 0)
  int bx = wg & 7, by = wg >> 3;
  int row0 = by << 8, col0 = bx << 7;
  int wrM = wid >> 1, wcN = wid & 1;

  const float* pA[4];
#pragma unroll
  for (int mi = 0; mi < 4; ++mi)
    pA[mi] = X + (size_t)(row0 + wrM * 64 + mi * 16 + fr) * 1024 + fg * 8;

  int rB = tid >> 2;
  int uswB = (((tid & 3) ^ ((tid >> 3) & 3)) << 3);
  const unsigned short* sK = Wkb + (size_t)(col0 + rB) * 1024 + uswB;
  const unsigned short* sV = Wvb + (size_t)(col0 + rB) * 1024 + uswB;
  int dK = wid << 9, dV = 4096 + (wid << 9);

  int ubo = (fg ^ ((fr >> 1) & 3)) << 3;
  int bro = (wcN * 64 + fr) * 32 + ubo;            // + ni*512; Bv at +4096

  f32x4 ck[4][4] = {{0}}, cv[4][4] = {{0}};
  f32x4 stgL[4], stgH[4];

  // prologue: A(0)->regs; B(0,1,2) via glds
#pragma unroll
  for (int mi = 0; mi < 4; ++mi) {
    stgL[mi] = *(const f32x4*)(pA[mi]);
    stgH[mi] = *(const f32x4*)(pA[mi] + 4);
  }
#pragma unroll
  for (int p = 0; p < 3; ++p) {
    int ko = p << 5;
    GLDS16(sK + ko, lds + p * DBUFS + dK);
    GLDS16(sV + ko, lds + p * DBUFS + dV);
  }
  asm volatile("s_waitcnt vmcnt(4)" ::: "memory");
  __builtin_amdgcn_s_barrier();

  for (int t = 0; t < NT; ++t) {
    const int rb = (t & 3) * DBUFS;
    const bool st1 = (t + 1 < NT);
    const bool st3 = (t + 3 < NT);
    const int ko1 = (t + 1) << 5;
    const int ko3 = (t + 3) << 5;
    const int wb3 = ((t + 3) & 3) * DBUFS;

    // half 1: pack A(t), issue A(t+1)+B(t+3), read bk, 16 MFMA ck
    bf16x8 a[4], bk[4];
#pragma unroll
    for (int mi = 0; mi < 4; ++mi) a[mi] = pack8(stgL[mi], stgH[mi]);
    if (st1) {
#pragma unroll
      for (int mi = 0; mi < 4; ++mi) {
        stgL[mi] = *(const f32x4*)(pA[mi] + ko1);
        stgH[mi] = *(const f32x4*)(pA[mi] + ko1 + 4);
      }
    }
    if (st3) {
      GLDS16(sK + ko3, lds + wb3 + dK);
      GLDS16(sV + ko3, lds + wb3 + dV);
    }
#pragma unroll
    for (int ni = 0; ni < 4; ++ni) bk[ni] = *(const bf16x8*)(lds + rb + bro + ni * 512);
    LGK0;
    __builtin_amdgcn_s_setprio(1);
#pragma unroll
    for (int mi = 0; mi < 4; ++mi)
#pragma unroll
      for (int ni = 0; ni < 4; ++ni)
        ck[mi][ni] = MFMA16(a[mi], bk[ni], ck[mi][ni]);
    __builtin_amdgcn_s_setprio(0);

    // half 2: read bv, 16 MFMA cv
    bf16x8 bv[4];
#pragma unroll
    for (int ni = 0; ni < 4; ++ni) bv[ni] = *(const bf16x8*)(lds + rb + 4096 + bro + ni * 512);
    LGK0;
    __builtin_amdgcn_s_setprio(1);
#pragma unroll
    for (int mi = 0; mi < 4; ++mi)
#pragma unroll
      for (int ni = 0; ni < 4; ++ni)
        cv[mi][ni] = MFMA16(a[mi], bv[ni], cv[mi][ni]);
    __builtin_amdgcn_s_setprio(0);

    // boundary: drain A(t+1) (+older B), keep B(t+3) in flight
    if (st1) {
      if (st3) { asm volatile("s_waitcnt vmcnt(2)" ::: "memory"); }
      else     { asm volatile("s_waitcnt vmcnt(0)" ::: "memory"); }
      __builtin_amdgcn_s_barrier();
    }
  }

  // epilogue: dots = per-head sum over 64 cols of ck*cv
  float part[4][4];
#pragma unroll
  for (int mi = 0; mi < 4; ++mi)
#pragma unroll
    for (int q = 0; q < 4; ++q) {
      float s = 0.f;
#pragma unroll
      for (int ni = 0; ni < 4; ++ni) s += ck[mi][ni][q] * cv[mi][ni][q];
      part[mi][q] = s;
    }
#pragma unroll
  for (int r = 0; r < 4; ++r) {
#pragma unroll
    for (int mi = 0; mi < 4; ++mi)
#pragma unroll
      for (int q = 0; q < 4; ++q)
        part[mi][q] += __shfl_xor(part[mi][q], 1 << r, 64);
  }
  int h = bx * 2 + wcN;
  if (fr == 0) {
#pragma unroll
    for (int mi = 0; mi < 4; ++mi)
#pragma unroll
      for (int q = 0; q < 4; ++q)
        dotsT[(size_t)h * 16384 + row0 + wrM * 64 + mi * 16 + fg * 4 + q] = part[mi][q];
  }
}

// ---------------- cumsum + coef + state ----------------
__global__ void k_cumsum(const float* __restrict__ dotsT, const float* __restrict__ dotbT,
                         const float* __restrict__ qsumT, const float* __restrict__ scal,
                         const float* __restrict__ mask,
                         float* __restrict__ coef, float* __restrict__ state) {
  __shared__ float csum[256];
  int b = blockIdx.x >> 4, h = blockIdx.x & 15;
  int t = threadIdx.x;
  float bqs = scal[h], dbc = scal[16 + h];
  size_t m0 = (size_t)b * 4096;
  const float* dro = dotsT + (size_t)h * 16384 + m0;
  const float* dbo = dotbT + (size_t)h * 16384 + m0;
  const float* qso = qsumT + (size_t)h * 16384 + m0;
  const float* mko = mask + m0;
  float loc[16], run = 0.f;
  int s0 = t * 16;
#pragma unroll
  for (int i = 0; i < 16; ++i) {
    int ii = s0 + i;
    float mk = mko[ii];
    float d = (dro[ii] + dbo[ii] + dbc) * mk * mk;
    run += d;
    loc[i] = run;
  }
  csum[t] = run;
  __syncthreads();
  for (int off = 1; off < 256; off <<= 1) {
    float v = (t >= off) ? csum[t - off] : 0.f;
    __syncthreads();
    csum[t] += v;
    __syncthreads();
  }
  float prefix = csum[t] - run;
#pragma unroll
  for (int i = 0; i < 16; ++i) {
    int ii = s0 + i;
    float cum = prefix + loc[i];
    coef[(m0 + ii) * 16 + h] = cum * (qso[ii] + bqs);
  }
  float total = csum[255];
  float* sp = state + (size_t)(b * 16 + h) * 4096;
  for (int i = t; i < 4096; i += 256) sp[i] = total;
}

// ---------------- output GEMM: out = coef(16384x16) @ WosT(16x1024) + bo ----------------
__global__ __launch_bounds__(256) void k_outgemm(const float* __restrict__ coef,
                                                 const float* __restrict__ WosT,
                                                 const float* __restrict__ bo,
                                                 float* __restrict__ out) {
  int t = threadIdx.x;
  int j0 = t * 4;
  f32x4 w4[16];
#pragma unroll
  for (int hh = 0; hh < 16; ++hh) w4[hh] = *(const f32x4*)&WosT[hh * 1024 + j0];
  f32x4 bov = *(const f32x4*)&bo[j0];
  size_t m0 = (size_t)blockIdx.x * 32;
  for (int mi = 0; mi < 32; ++mi) {
    size_t m = m0 + mi;
    const float* cm = &coef[m * 16];
    f32x4 acc = bov;
#pragma unroll
    for (int hh = 0; hh < 16; ++hh) acc += w4[hh] * cm[hh];
    *(f32x4*)&out[m * 1024 + j0] = acc;
  }
}

extern "C" void kernel_launch(void* const* d_in, const int* in_sizes, int n_in,
                              void* d_out, int out_size, void* d_ws, size_t ws_size,
                              hipStream_t stream) {
  const float* X    = (const float*)d_in[0];
  const float* mask = (const float*)d_in[1];
  const float* Wq   = (const float*)d_in[2];
  const float* bq   = (const float*)d_in[3];
  const float* Wk   = (const float*)d_in[4];
  const float* bk   = (const float*)d_in[5];
  const float* Wv   = (const float*)d_in[6];
  const float* bv   = (const float*)d_in[7];
  const float* Wo   = (const float*)d_in[8];
  const float* bo   = (const float*)d_in[9];
  float* out   = (float*)d_out;
  float* state = out + (size_t)16384 * 1024;

  char* w = (char*)d_ws;
  unsigned short* Wkb = (unsigned short*)w; w += (size_t)1024 * 1024 * 2;
  unsigned short* Wvb = (unsigned short*)w; w += (size_t)1024 * 1024 * 2;
  unsigned short* SWb = (unsigned short*)w; w += (size_t)32 * 1024 * 2;
  float* WosT  = (float*)w; w += (size_t)16 * 1024 * 4;
  float* scal  = (float*)w; w += 256;
  float* dotsT = (float*)w; w += (size_t)16 * 16384 * 4;
  float* qsumT = (float*)w; w += (size_t)16 * 16384 * 4;
  float* dotbT = (float*)w; w += (size_t)16 * 16384 * 4;
  float* coef  = (float*)w; w += (size_t)16384 * 16 * 4;

  (void)hipFuncSetAttribute((const void*)k_dualgemm,
                            hipFuncAttributeMaxDynamicSharedMemorySize, 67584);

  hipLaunchKernelGGL(k_prep,     dim3(2241), dim3(256), 0, stream,
                     Wq, bq, Wk, bk, Wv, bv, Wo, Wkb, Wvb, SWb, WosT, scal);
  hipLaunchKernelGGL(k_dualgemm, dim3(576),  dim3(512), 67584, stream, X, Wkb, Wvb, SWb,
                     dotsT, qsumT, dotbT);
  hipLaunchKernelGGL(k_cumsum,   dim3(64),   dim3(256), 0, stream, dotsT, dotbT, qsumT, scal,
                     mask, coef, state);
  hipLaunchKernelGGL(k_outgemm,  dim3(512),  dim3(256), 0, stream, coef, WosT, bo, out);
}

// Round 11
// 110.364 us; speedup vs baseline: 2.2006x; 2.2006x over previous
//
#include <hip/hip_runtime.h>

// LinearAttention collapsed:
//   dots[m,h] = sum_{d in head h} (X@Wk^T)*(X@Wv^T)   [dual GEMM, R1-proven core]
//   qsum = X @ Wqs^T ; dotb = X @ CB^T                 [piggybacked on bx==0 blocks]
//   cum = cumsum_s((dots + dotb + dbc)*mask^2); coef = cum*(qsum+bqs)
//   out = coef @ WosT + bo ; state[b,h,:,:] = cum[b, S-1, h]

typedef __attribute__((ext_vector_type(4))) float f32x4;
typedef __attribute__((ext_vector_type(8))) short bf16x8;
typedef __attribute__((ext_vector_type(8))) unsigned short u16x8;
typedef unsigned int u32;

#define GLDS16(g, l)                                                            \
  __builtin_amdgcn_global_load_lds((const __attribute__((address_space(1))) u32*)(g), \
                                   (__attribute__((address_space(3))) u32*)(l), 16, 0, 0)
#define MFMA16(a, b, c) __builtin_amdgcn_mfma_f32_16x16x32_bf16(a, b, c, 0, 0, 0)
#define LGK0 do { asm volatile("s_waitcnt lgkmcnt(0)" ::: "memory"); \
                  __builtin_amdgcn_sched_barrier(0); } while (0)

__device__ __forceinline__ unsigned short f2bf(float f) {
  union { float f; u32 u; } x; x.f = f;
  u32 r = (x.u + 0x7fffu + ((x.u >> 16) & 1u)) >> 16;
  return (unsigned short)r;
}

// ---------------- fused prep: Wk/Wv->bf16, weight sums, X->bf16 ----------------
__global__ void k_prep(const float* __restrict__ X, unsigned short* __restrict__ Xb,
                       const float* __restrict__ Wq, const float* __restrict__ bq,
                       const float* __restrict__ Wk, const float* __restrict__ bk,
                       const float* __restrict__ Wv, const float* __restrict__ bv,
                       const float* __restrict__ Wo,
                       unsigned short* __restrict__ Wkb, unsigned short* __restrict__ Wvb,
                       unsigned short* __restrict__ SWb, float* __restrict__ WosT,
                       float* __restrict__ scal) {
  int blk = blockIdx.x, t = threadIdx.x;
  if (blk < 2048) {                    // Wk/Wv convert
    const float* src = (blk < 1024) ? Wk : Wv;
    unsigned short* dst = (blk < 1024) ? Wkb : Wvb;
    size_t i = ((size_t)(blk & 1023) * 256 + t) * 4;
    f32x4 v = *(const f32x4*)(src + i);
    dst[i + 0] = f2bf(v.x); dst[i + 1] = f2bf(v.y);
    dst[i + 2] = f2bf(v.z); dst[i + 3] = f2bf(v.w);
  } else if (blk < 2241) {             // weight sums
    int b2 = blk - 2048;
    if (b2 < 128) {
      int o = b2 * 256 + t;
      int r = o >> 10, c = o & 1023;
      float s = 0.f;
      if (r < 16) {
        for (int d = 0; d < 64; ++d) s += Wq[(size_t)(r * 64 + d) * 1024 + c];
      } else {
        int h = r - 16;
        for (int d = 0; d < 64; ++d) {
          int j = h * 64 + d;
          s += bv[j] * Wk[(size_t)j * 1024 + c] + bk[j] * Wv[(size_t)j * 1024 + c];
        }
      }
      SWb[o] = f2bf(s);
    } else if (b2 < 192) {
      int o = (b2 - 128) * 256 + t;
      int h = o >> 10, j = o & 1023;
      float s = 0.f;
      for (int d = 0; d < 64; ++d) s += Wo[(size_t)j * 1024 + h * 64 + d];
      WosT[o] = s;
    } else {
      if (t < 16) {
        float s = 0.f;
        for (int d = 0; d < 64; ++d) s += bq[t * 64 + d];
        scal[t] = s;
      } else if (t < 32) {
        int h = t - 16;
        float s = 0.f;
        for (int d = 0; d < 64; ++d) s += bk[h * 64 + d] * bv[h * 64 + d];
        scal[t] = s;
      }
    }
  } else {                             // X convert
    size_t i = ((size_t)(blk - 2241) * 256 + t) * 8;
    f32x4 a = *(const f32x4*)(X + i);
    f32x4 b = *(const f32x4*)(X + i + 4);
    u16x8 o;
    o[0] = f2bf(a.x); o[1] = f2bf(a.y); o[2] = f2bf(a.z); o[3] = f2bf(a.w);
    o[4] = f2bf(b.x); o[5] = f2bf(b.y); o[6] = f2bf(b.z); o[7] = f2bf(b.w);
    *(u16x8*)(Xb + i) = o;
  }
}

// ---------------- dual GEMM (R1-proven core) + piggybacked side ----------------
// BM=256, BN=128, BK=32, 8 waves (4M x 2N), 4 LDS buffers, prefetch depth 3,
// ONE barrier/tile with loop-top counted vmcnt. Buffer (elems): A@0 (8192),
// Bk@8192 (4096), Bv@12288 (4096), SW@16384 (1024) = 17408; 4 bufs = 139264 B.
// bf16 rows 64B = 4x16B units; swizzle key (row>>1)&3 on source and read (0-conflict).
// Per-thread glds/tile: 4 (A0,K | A1,V); swv threads 5 (+SW) -> loop-top vmcnt 8 / 10.
#define NT 32
#define BUFS 17408
__global__ __launch_bounds__(512, 1) void k_dualgemm(
    const unsigned short* __restrict__ Xb,
    const unsigned short* __restrict__ Wkb,
    const unsigned short* __restrict__ Wvb,
    const unsigned short* __restrict__ SWb,
    float* __restrict__ dotsT, float* __restrict__ qsumT, float* __restrict__ dotbT) {
  extern __shared__ __align__(16) unsigned short lds[];
  int orig = blockIdx.x;
  int wg = (orig & 7) * 64 + (orig >> 3);    // XCD-chunked swizzle (512 % 8 == 0)
  int bx = wg & 7, by = wg >> 3;
  int row0 = by << 8, col0 = bx << 7;
  int tid = threadIdx.x, wid = tid >> 6, lane = tid & 63;
  int wrM = wid >> 1, wcN = wid & 1;
  int fr = lane & 15, fg = lane >> 4;
  bool side = (bx == 0);
  bool swv = side && (wid < 2);

  // staging sources (pre-swizzled 16B units)
  int uA0 = tid, uA1 = tid + 512;
  const unsigned short* sA0 = Xb + (size_t)(row0 + (uA0 >> 2)) * 1024 + (((uA0 & 3) ^ ((uA0 >> 3) & 3)) << 3);
  const unsigned short* sA1 = Xb + (size_t)(row0 + (uA1 >> 2)) * 1024 + (((uA1 & 3) ^ ((uA1 >> 3) & 3)) << 3);
  const unsigned short* sK  = Wkb + (size_t)(col0 + (tid >> 2)) * 1024 + (((tid & 3) ^ ((tid >> 3) & 3)) << 3);
  const unsigned short* sV  = Wvb + (size_t)(col0 + (tid >> 2)) * 1024 + (((tid & 3) ^ ((tid >> 3) & 3)) << 3);
  const unsigned short* sS  = SWb + (size_t)(tid >> 2) * 1024 + (((tid & 3) ^ ((tid >> 3) & 3)) << 3);  // tid<128
  // wave-uniform LDS dest bases (elements, within buffer)
  int dA0 = wid << 9, dA1 = 4096 + (wid << 9);
  int dK = 8192 + (wid << 9), dV = 12288 + (wid << 9);
  int dS = 16384 + (wid << 9);     // only wid<2 of side blocks

  // fragment read offsets (swizzled, R1-proven)
  int xsw = (fg ^ ((fr >> 1) & 3)) << 3;
  int aro = (wrM * 64 + fr) * 32 + xsw;            // + mi*512
  int bro = (wcN * 64 + fr) * 32 + xsw;            // + ni*512 (+8192 Bk, +12288 Bv)
  int swo = 16384 + (wcN * 16 + fr) * 32 + xsw;    // wcN=0: Wqs rows, wcN=1: CB rows

  f32x4 ck[4][4] = {{0}}, cv[4][4] = {{0}};
  f32x4 qa[4] = {0, 0, 0, 0};

  // prologue: stage tiles 0,1,2
#pragma unroll
  for (int p = 0; p < 3; ++p) {
    int bb = p * BUFS, ko = p * 32;
    GLDS16(sA0 + ko, lds + bb + dA0);
    GLDS16(sK + ko, lds + bb + dK);
    GLDS16(sA1 + ko, lds + bb + dA1);
    GLDS16(sV + ko, lds + bb + dV);
    if (swv) GLDS16(sS + ko, lds + bb + dS);
  }

  for (int t = 0; t < NT; ++t) {
    int rb = (t & 3) * BUFS;
    if (t < NT - 3) {
      if (swv) { asm volatile("s_waitcnt vmcnt(10)" ::: "memory"); }
      else     { asm volatile("s_waitcnt vmcnt(8)"  ::: "memory"); }
    } else {
      asm volatile("s_waitcnt vmcnt(0)" ::: "memory");
    }
    __builtin_amdgcn_s_barrier();
    __builtin_amdgcn_sched_barrier(0);

    bf16x8 a[4], bk[4], bv[4];
#pragma unroll
    for (int mi = 0; mi < 4; ++mi) a[mi] = *(const bf16x8*)(lds + rb + aro + mi * 512);
#pragma unroll
    for (int ni = 0; ni < 2; ++ni) {
      bk[ni] = *(const bf16x8*)(lds + rb + 8192 + bro + ni * 512);
      bv[ni] = *(const bf16x8*)(lds + rb + 12288 + bro + ni * 512);
    }
    int t3 = t + 3;
    int bb = (t3 & 3) * BUFS, ko = t3 << 5;
    if (t3 < NT) {
      GLDS16(sA0 + ko, lds + bb + dA0);
      GLDS16(sK + ko, lds + bb + dK);
    }
    LGK0;
    __builtin_amdgcn_s_setprio(1);
#pragma unroll
    for (int mi = 0; mi < 4; ++mi)
#pragma unroll
      for (int ni = 0; ni < 2; ++ni) {
        ck[mi][ni] = MFMA16(a[mi], bk[ni], ck[mi][ni]);
        cv[mi][ni] = MFMA16(a[mi], bv[ni], cv[mi][ni]);
      }
    __builtin_amdgcn_s_setprio(0);

#pragma unroll
    for (int ni = 2; ni < 4; ++ni) {
      bk[ni] = *(const bf16x8*)(lds + rb + 8192 + bro + ni * 512);
      bv[ni] = *(const bf16x8*)(lds + rb + 12288 + bro + ni * 512);
    }
    bf16x8 sw;
    if (side) sw = *(const bf16x8*)(lds + rb + swo);
    if (t3 < NT) {
      GLDS16(sA1 + ko, lds + bb + dA1);
      GLDS16(sV + ko, lds + bb + dV);
      if (swv) GLDS16(sS + ko, lds + bb + dS);
    }
    LGK0;
    __builtin_amdgcn_s_setprio(1);
#pragma unroll
    for (int mi = 0; mi < 4; ++mi)
#pragma unroll
      for (int ni = 2; ni < 4; ++ni) {
        ck[mi][ni] = MFMA16(a[mi], bk[ni], ck[mi][ni]);
        cv[mi][ni] = MFMA16(a[mi], bv[ni], cv[mi][ni]);
      }
    if (side) {
#pragma unroll
      for (int mi = 0; mi < 4; ++mi) qa[mi] = MFMA16(a[mi], sw, qa[mi]);
    }
    __builtin_amdgcn_s_setprio(0);
  }

  // epilogue: dots = per-head sum over 64 cols of ck*cv
  float part[4][4];
#pragma unroll
  for (int mi = 0; mi < 4; ++mi)
#pragma unroll
    for (int q = 0; q < 4; ++q) {
      float s = 0.f;
#pragma unroll
      for (int ni = 0; ni < 4; ++ni) s += ck[mi][ni][q] * cv[mi][ni][q];
      part[mi][q] = s;
    }
#pragma unroll
  for (int r = 0; r < 4; ++r) {
#pragma unroll
    for (int mi = 0; mi < 4; ++mi)
#pragma unroll
      for (int q = 0; q < 4; ++q)
        part[mi][q] += __shfl_xor(part[mi][q], 1 << r, 64);
  }
  int h = bx * 2 + wcN;
  if (fr == 0) {
#pragma unroll
    for (int mi = 0; mi < 4; ++mi)
#pragma unroll
      for (int q = 0; q < 4; ++q)
        dotsT[(size_t)h * 16384 + row0 + wrM * 64 + mi * 16 + fg * 4 + q] = part[mi][q];
  }
  if (side) {
    float* dst = (wcN == 0) ? qsumT : dotbT;   // C/D col (lane&15) == side-head index
#pragma unroll
    for (int mi = 0; mi < 4; ++mi)
#pragma unroll
      for (int q = 0; q < 4; ++q)
        dst[(size_t)fr * 16384 + row0 + wrM * 64 + mi * 16 + fg * 4 + q] = qa[mi][q];
  }
}

// ---------------- cumsum + coef + state ----------------
__global__ void k_cumsum(const float* __restrict__ dotsT, const float* __restrict__ dotbT,
                         const float* __restrict__ qsumT, const float* __restrict__ scal,
                         const float* __restrict__ mask,
                         float* __restrict__ coef, float* __restrict__ state) {
  __shared__ float csum[256];
  int b = blockIdx.x >> 4, h = blockIdx.x & 15;
  int t = threadIdx.x;
  float bqs = scal[h], dbc = scal[16 + h];
  size_t m0 = (size_t)b * 4096;
  const float* dro = dotsT + (size_t)h * 16384 + m0;
  const float* dbo = dotbT + (size_t)h * 16384 + m0;
  const float* qso = qsumT + (size_t)h * 16384 + m0;
  const float* mko = mask + m0;
  float loc[16], run = 0.f;
  int s0 = t * 16;
#pragma unroll
  for (int i = 0; i < 16; ++i) {
    int ii = s0 + i;
    float mk = mko[ii];
    float d = (dro[ii] + dbo[ii] + dbc) * mk * mk;
    run += d;
    loc[i] = run;
  }
  csum[t] = run;
  __syncthreads();
  for (int off = 1; off < 256; off <<= 1) {
    float v = (t >= off) ? csum[t - off] : 0.f;
    __syncthreads();
    csum[t] += v;
    __syncthreads();
  }
  float prefix = csum[t] - run;
#pragma unroll
  for (int i = 0; i < 16; ++i) {
    int ii = s0 + i;
    float cum = prefix + loc[i];
    coef[(m0 + ii) * 16 + h] = cum * (qso[ii] + bqs);
  }
  float total = csum[255];
  float* sp = state + (size_t)(b * 16 + h) * 4096;
  for (int i = t; i < 4096; i += 256) sp[i] = total;
}

// ---------------- output GEMM: out = coef(16384x16) @ WosT(16x1024) + bo ----------------
__global__ __launch_bounds__(256) void k_outgemm(const float* __restrict__ coef,
                                                 const float* __restrict__ WosT,
                                                 const float* __restrict__ bo,
                                                 float* __restrict__ out) {
  int t = threadIdx.x;
  int j0 = t * 4;
  f32x4 w4[16];
#pragma unroll
  for (int hh = 0; hh < 16; ++hh) w4[hh] = *(const f32x4*)&WosT[hh * 1024 + j0];
  f32x4 bov = *(const f32x4*)&bo[j0];
  size_t m0 = (size_t)blockIdx.x * 32;
  for (int mi = 0; mi < 32; ++mi) {
    size_t m = m0 + mi;
    const float* cm = &coef[m * 16];
    f32x4 acc = bov;
#pragma unroll
    for (int hh = 0; hh < 16; ++hh) acc += w4[hh] * cm[hh];
    *(f32x4*)&out[m * 1024 + j0] = acc;
  }
}

extern "C" void kernel_launch(void* const* d_in, const int* in_sizes, int n_in,
                              void* d_out, int out_size, void* d_ws, size_t ws_size,
                              hipStream_t stream) {
  const float* X    = (const float*)d_in[0];
  const float* mask = (const float*)d_in[1];
  const float* Wq   = (const float*)d_in[2];
  const float* bq   = (const float*)d_in[3];
  const float* Wk   = (const float*)d_in[4];
  const float* bk   = (const float*)d_in[5];
  const float* Wv   = (const float*)d_in[6];
  const float* bv   = (const float*)d_in[7];
  const float* Wo   = (const float*)d_in[8];
  const float* bo   = (const float*)d_in[9];
  float* out   = (float*)d_out;
  float* state = out + (size_t)16384 * 1024;

  char* w = (char*)d_ws;
  unsigned short* Xb  = (unsigned short*)w; w += (size_t)16384 * 1024 * 2;
  unsigned short* Wkb = (unsigned short*)w; w += (size_t)1024 * 1024 * 2;
  unsigned short* Wvb = (unsigned short*)w; w += (size_t)1024 * 1024 * 2;
  unsigned short* SWb = (unsigned short*)w; w += (size_t)32 * 1024 * 2;
  float* WosT  = (float*)w; w += (size_t)16 * 1024 * 4;
  float* scal  = (float*)w; w += 256;
  float* dotsT = (float*)w; w += (size_t)16 * 16384 * 4;
  float* qsumT = (float*)w; w += (size_t)16 * 16384 * 4;
  float* dotbT = (float*)w; w += (size_t)16 * 16384 * 4;
  float* coef  = (float*)w; w += (size_t)16384 * 16 * 4;

  (void)hipFuncSetAttribute((const void*)k_dualgemm,
                            hipFuncAttributeMaxDynamicSharedMemorySize, 139264);

  hipLaunchKernelGGL(k_prep,     dim3(10433), dim3(256), 0, stream,
                     X, Xb, Wq, bq, Wk, bk, Wv, bv, Wo, Wkb, Wvb, SWb, WosT, scal);
  hipLaunchKernelGGL(k_dualgemm, dim3(512),  dim3(512), 139264, stream, Xb, Wkb, Wvb, SWb,
                     dotsT, qsumT, dotbT);
  hipLaunchKernelGGL(k_cumsum,   dim3(64),   dim3(256), 0, stream, dotsT, dotbT, qsumT, scal,
                     mask, coef, state);
  hipLaunchKernelGGL(k_outgemm,  dim3(512),  dim3(256), 0, stream, coef, WosT, bo, out);
}